// Round 1
// baseline (1119.207 us; speedup 1.0000x reference)
//
#include <hip/hip_runtime.h>
#include <hip/hip_bf16.h>
#include <stdint.h>

#define C_DIM 768
#define HW 16384
#define EPSF 1e-8f

typedef __attribute__((ext_vector_type(8))) __bf16 bf16x8;
typedef __attribute__((ext_vector_type(4))) float floatx4;

// ---------------- Kernel A: per-channel means over spatial dim ----------------
__global__ __launch_bounds__(256) void k_means(const float* __restrict__ x,
                                               const float* __restrict__ s,
                                               float* __restrict__ meanA,
                                               float* __restrict__ meanB) {
  int ch = blockIdx.x;
  const float* src = (ch < C_DIM) ? (x + (size_t)ch * HW) : (s + (size_t)(ch - C_DIM) * HW);
  int t = threadIdx.x;
  float acc = 0.f;
  for (int i = t; i < HW; i += 256) acc += src[i];
  __shared__ float red[256];
  red[t] = acc;
  __syncthreads();
  for (int o = 128; o > 0; o >>= 1) {
    if (t < o) red[t] += red[t + o];
    __syncthreads();
  }
  if (t == 0) {
    float m = red[0] * (1.0f / HW);
    if (ch < C_DIM) meanA[ch] = m; else meanB[ch - C_DIM] = m;
  }
}

// ---------------- Kernel B: norms + centered bf16 transpose ----------------
// Produces:
//   Abf[j][c] = bf16(x[c][j] - meanA[c])            (16384 x 768, K-contiguous)
//   Bbf[j][c] = bf16(s[c][j] - meanB[c])
//   invbn[j]  = 1/(sqrt(sum_c (s-mb)^2 + EPS) + EPS)
//   rawNA[j]  = sqrt(sum_c x^2),  rawNB[j] = sqrt(sum_c s^2)
__global__ __launch_bounds__(256) void k_prep(const float* __restrict__ x,
                                              const float* __restrict__ s,
                                              const float* __restrict__ meanA,
                                              const float* __restrict__ meanB,
                                              __hip_bfloat16* __restrict__ Abf,
                                              __hip_bfloat16* __restrict__ Bbf,
                                              float* __restrict__ invbn,
                                              float* __restrict__ rawNA,
                                              float* __restrict__ rawNB) {
  __shared__ float la[64 * 33];   // [col][r], stride 33 kills bank conflicts
  __shared__ float lb[64 * 33];
  __shared__ float lma[C_DIM];
  __shared__ float lmb[C_DIM];
  __shared__ float red[3 * 256];
  int t = threadIdx.x;
  int j0 = blockIdx.x * 64;
  for (int c = t; c < C_DIM; c += 256) { lma[c] = meanA[c]; lmb[c] = meanB[c]; }

  int col = t & 63;  // position within tile (for reduction)
  int rr = t >> 6;   // 0..3
  float ssa = 0.f, ssb = 0.f, cssb = 0.f;

  for (int c0 = 0; c0 < C_DIM; c0 += 32) {
    __syncthreads();  // protect LDS tiles (also covers the mean preload on iter 0)
#pragma unroll
    for (int sIt = 0; sIt < 8; ++sIt) {
      int idx = t + sIt * 256;
      int r = idx >> 6, cc = idx & 63;
      la[cc * 33 + r] = x[(size_t)(c0 + r) * HW + j0 + cc];
      lb[cc * 33 + r] = s[(size_t)(c0 + r) * HW + j0 + cc];
    }
    __syncthreads();
#pragma unroll
    for (int q = 0; q < 8; ++q) {
      int r = rr * 8 + q;
      float av = la[col * 33 + r];
      float bv = lb[col * 33 + r];
      ssa += av * av;
      ssb += bv * bv;
      float bc = bv - lmb[c0 + r];
      cssb += bc * bc;
    }
    // transposed bf16 writes: [j][c] layout, K contiguous
#pragma unroll
    for (int sIt = 0; sIt < 8; ++sIt) {
      int idx = t + sIt * 256;
      int j = idx >> 5, k = idx & 31;
      float av = la[j * 33 + k] - lma[c0 + k];
      float bv = lb[j * 33 + k] - lmb[c0 + k];
      Abf[(size_t)(j0 + j) * C_DIM + c0 + k] = __float2bfloat16(av);
      Bbf[(size_t)(j0 + j) * C_DIM + c0 + k] = __float2bfloat16(bv);
    }
  }
  red[t] = ssa; red[256 + t] = ssb; red[512 + t] = cssb;
  __syncthreads();
  if (t < 64) {
    float sa = red[t] + red[t + 64] + red[t + 128] + red[t + 192];
    float sb = red[256 + t] + red[256 + t + 64] + red[256 + t + 128] + red[256 + t + 192];
    float sc = red[512 + t] + red[512 + t + 64] + red[512 + t + 128] + red[512 + t + 192];
    rawNA[j0 + t] = sqrtf(sa);
    rawNB[j0 + t] = sqrtf(sb);
    invbn[j0 + t] = 1.0f / (sqrtf(sc + EPSF) + EPSF);
  }
}

// ---------------- Kernel C: MFMA GEMM with fused argmax epilogue ----------------
__device__ __forceinline__ void gl_lds16(const void* g, void* l) {
  __builtin_amdgcn_global_load_lds((const __attribute__((address_space(1))) uint32_t*)g,
                                   (__attribute__((address_space(3))) uint32_t*)l, 16, 0, 0);
}

__global__ __launch_bounds__(256) void k_gemm_argmax(
    const __hip_bfloat16* __restrict__ Abf,
    const __hip_bfloat16* __restrict__ Bbf,
    const float* __restrict__ invbn,
    unsigned long long* __restrict__ best) {
  __shared__ alignas(16) __hip_bfloat16 As[128 * 32];
  __shared__ alignas(16) __hip_bfloat16 Bs[128 * 32];
  int t = threadIdx.x;
  int bx = blockIdx.x & 127;
  int by = blockIdx.x >> 7;
  int i0 = by * 128, j0 = bx * 128;
  int lane = t & 63, w = t >> 6;
  int wm = w >> 1, wn = w & 1;

  floatx4 acc[4][4];
#pragma unroll
  for (int a1 = 0; a1 < 4; ++a1)
#pragma unroll
    for (int a2 = 0; a2 < 4; ++a2) acc[a1][a2] = (floatx4){0.f, 0.f, 0.f, 0.f};

  // staging: thread t -> row t/4, 16B chunk t%4; LDS offset = t*16 bytes (lane-linear)
  int srow = t >> 2;
  int scol = (t & 3) * 8;
  const __hip_bfloat16* aSrc = Abf + (size_t)(i0 + srow) * C_DIM + scol;
  const __hip_bfloat16* bSrc = Bbf + (size_t)(j0 + srow) * C_DIM + scol;
  __hip_bfloat16* aDst = &As[t * 8];
  __hip_bfloat16* bDst = &Bs[t * 8];
  const size_t rowSkip = (size_t)64 * C_DIM;

  int mrow = lane & 15;
  int kq = (lane >> 4) * 8;

  for (int k0 = 0; k0 < C_DIM; k0 += 32) {
    __syncthreads();
    gl_lds16(aSrc + k0, aDst);
    gl_lds16(aSrc + k0 + rowSkip, aDst + 64 * 32);
    gl_lds16(bSrc + k0, bDst);
    gl_lds16(bSrc + k0 + rowSkip, bDst + 64 * 32);
    __syncthreads();
    bf16x8 af[4], bfr[4];
#pragma unroll
    for (int tm = 0; tm < 4; ++tm)
      af[tm] = *(const bf16x8*)&As[(wm * 64 + tm * 16 + mrow) * 32 + kq];
#pragma unroll
    for (int tn = 0; tn < 4; ++tn)
      bfr[tn] = *(const bf16x8*)&Bs[(wn * 64 + tn * 16 + mrow) * 32 + kq];
#pragma unroll
    for (int tm = 0; tm < 4; ++tm)
#pragma unroll
      for (int tn = 0; tn < 4; ++tn)
        acc[tm][tn] = __builtin_amdgcn_mfma_f32_16x16x32_bf16(af[tm], bfr[tn], acc[tm][tn], 0, 0, 0);
  }

  // epilogue: apply per-column 1/bn_j, per-row argmax, packed atomicMax
  int colid = lane & 15;
  int quad = lane >> 4;
  float ib[4];
#pragma unroll
  for (int tn = 0; tn < 4; ++tn) ib[tn] = invbn[j0 + wn * 64 + tn * 16 + colid];

#pragma unroll
  for (int tm = 0; tm < 4; ++tm) {
#pragma unroll
    for (int r = 0; r < 4; ++r) {
      int i = i0 + wm * 64 + tm * 16 + quad * 4 + r;
      float bestv = -3.0e38f;
      int bestj = 0x7FFFFFFF;
#pragma unroll
      for (int tn = 0; tn < 4; ++tn) {
        int j = j0 + wn * 64 + tn * 16 + colid;
        float v = acc[tm][tn][r] * ib[tn];
        if (v > bestv) { bestv = v; bestj = j; }   // strict >: lowest j wins ties
      }
#pragma unroll
      for (int off = 1; off < 16; off <<= 1) {
        float ov = __shfl_xor(bestv, off, 64);
        int oj = __shfl_xor(bestj, off, 64);
        if (ov > bestv || (ov == bestv && oj < bestj)) { bestv = ov; bestj = oj; }
      }
      if (colid == 0) {
        unsigned key = __float_as_uint(bestv);
        key = (key & 0x80000000u) ? ~key : (key | 0x80000000u);
        unsigned long long packed =
            ((unsigned long long)key << 32) | (unsigned long long)(0xFFFFFFFFu - (unsigned)bestj);
        atomicMax(&best[i], packed);
      }
    }
  }
}

// ---------------- Kernel D: final cosine loss on raw columns ----------------
__global__ __launch_bounds__(256) void k_loss(const float* __restrict__ x,
                                              const float* __restrict__ s,
                                              const unsigned long long* __restrict__ best,
                                              const float* __restrict__ rawNA,
                                              const float* __restrict__ rawNB,
                                              float* __restrict__ out) {
  int i = blockIdx.x * 256 + threadIdx.x;
  unsigned j = 0xFFFFFFFFu - (unsigned)(best[i] & 0xFFFFFFFFull);
  float dot = 0.f;
  for (int c = 0; c < C_DIM; ++c)
    dot += x[(size_t)c * HW + i] * s[(size_t)c * HW + j];
  float cs = dot / ((rawNA[i] + EPSF) * (rawNB[j] + EPSF));
  float term = (1.0f - cs) * (1.0f / HW);
  __shared__ float red[256];
  int t = threadIdx.x;
  red[t] = term;
  __syncthreads();
  for (int o = 128; o > 0; o >>= 1) {
    if (t < o) red[t] += red[t + o];
    __syncthreads();
  }
  if (t == 0) atomicAdd(out, red[0]);
}

// ---------------- Launch ----------------
extern "C" void kernel_launch(void* const* d_in, const int* in_sizes, int n_in,
                              void* d_out, int out_size, void* d_ws, size_t ws_size,
                              hipStream_t stream) {
  const float* x = (const float*)d_in[0];
  const float* s = (const float*)d_in[1];
  char* ws = (char*)d_ws;
  // workspace layout (total ~48.5 MB)
  float* meanA = (float*)(ws + 0);
  float* meanB = (float*)(ws + 4096);
  float* invbn = (float*)(ws + 8192);
  float* rawNA = (float*)(ws + 73728);
  float* rawNB = (float*)(ws + 139264);
  unsigned long long* best = (unsigned long long*)(ws + 204800);
  __hip_bfloat16* Abf = (__hip_bfloat16*)(ws + 524288);
  __hip_bfloat16* Bbf = (__hip_bfloat16*)(ws + 524288 + 25165824);
  float* out = (float*)d_out;

  hipMemsetAsync(best, 0, HW * sizeof(unsigned long long), stream);
  hipMemsetAsync(out, 0, sizeof(float), stream);
  k_means<<<2 * C_DIM, 256, 0, stream>>>(x, s, meanA, meanB);
  k_prep<<<HW / 64, 256, 0, stream>>>(x, s, meanA, meanB, Abf, Bbf, invbn, rawNA, rawNB);
  k_gemm_argmax<<<(HW / 128) * (HW / 128), 256, 0, stream>>>(Abf, Bbf, invbn, best);
  k_loss<<<HW / 256, 256, 0, stream>>>(x, s, best, rawNA, rawNB, out);
}